// Round 4
// baseline (510.423 us; speedup 1.0000x reference)
//
#include <hip/hip_runtime.h>
#include <hip/hip_fp16.h>

// GCN 2-layer, CSR-gather formulation, fp16 storage / fp32 math.
// Agg(X@W) == Agg(X)@W. norm = dinv[r]*dinv[c] factored:
//   y = half(x * dinv)
//   aggX[c] = half( dinv[c] * (y[c] + sum_{r in in(c)} y[r]) )
//   h1 = half( relu(aggX @ W1 + b1) )
//   z  = half( (h1 @ W2) * dinv )
//   out[c] = fp32( dinv[c] * (z[c] + sum z[r]) + b2 )
// CSR built via 2-phase binning (bucket = dst>>4) so all scatter stores are
// line-dense: direct random 4B stores write-through ~64B/line (105 MB for a
// 6.4 MB array, measured round 3).

constexpr int NN = 100000;   // nodes
constexpr int NE = 1600000;  // edges
constexpr int BSH = 4;       // bucket shift: 16 nodes/bucket
constexpr int NB = NN >> BSH;  // 6250 buckets (NN divisible by 16)

// ---------------- degree histogram (int atomics, L2-resident) ----------------
__global__ __launch_bounds__(256) void k_deg(const int* __restrict__ cols,
                                             int* __restrict__ deg) {
  int e = blockIdx.x * 256 + threadIdx.x;
  if (e < NE) atomicAdd(&deg[cols[e]], 1);
}

// ---------------- exclusive scan of deg -> rowptr (3 kernels) ----------------
__global__ __launch_bounds__(256) void k_scanA(const int* __restrict__ deg,
                                               int* __restrict__ rowptr,
                                               int* __restrict__ blockSum) {
  __shared__ int s[256];
  int t = threadIdx.x, b = blockIdx.x;
  int base = b * 1024 + t * 4;
  int d0 = (base + 0 < NN) ? deg[base + 0] : 0;
  int d1 = (base + 1 < NN) ? deg[base + 1] : 0;
  int d2 = (base + 2 < NN) ? deg[base + 2] : 0;
  int d3 = (base + 3 < NN) ? deg[base + 3] : 0;
  int tsum = d0 + d1 + d2 + d3;
  s[t] = tsum;
  __syncthreads();
  for (int off = 1; off < 256; off <<= 1) {
    int tmp = (t >= off) ? s[t - off] : 0;
    __syncthreads();
    s[t] += tmp;
    __syncthreads();
  }
  int ex = s[t] - tsum;
  if (base + 0 < NN) rowptr[base + 0] = ex;
  if (base + 1 < NN) rowptr[base + 1] = ex + d0;
  if (base + 2 < NN) rowptr[base + 2] = ex + d0 + d1;
  if (base + 3 < NN) rowptr[base + 3] = ex + d0 + d1 + d2;
  if (t == 255) blockSum[b] = ex + tsum;
}

__global__ __launch_bounds__(128) void k_scanB(int* __restrict__ blockSum,
                                               int* __restrict__ blockOff,
                                               int nblocks) {
  __shared__ int s[128];
  int t = threadIdx.x;
  int v = (t < nblocks) ? blockSum[t] : 0;
  s[t] = v;
  __syncthreads();
  for (int off = 1; off < 128; off <<= 1) {
    int tmp = (t >= off) ? s[t - off] : 0;
    __syncthreads();
    s[t] += tmp;
    __syncthreads();
  }
  if (t < nblocks) blockOff[t] = s[t] - v;
}

__global__ __launch_bounds__(256) void k_scanC(int* __restrict__ rowptr,
                                               const int* __restrict__ blockOff,
                                               const int* __restrict__ deg,
                                               float* __restrict__ dinv) {
  int i = blockIdx.x * 256 + threadIdx.x;
  if (i < NN) {
    rowptr[i] += blockOff[i >> 10];
    dinv[i] = rsqrtf((float)deg[i] + 1.0f);
  }
}

// bucketPtr[b] (padded to 64B) = rowptr[b*16]
__global__ __launch_bounds__(256) void k_binit(const int* __restrict__ rowptr,
                                               int* __restrict__ bucketPtr) {
  int b = blockIdx.x * 256 + threadIdx.x;
  if (b < NB) bucketPtr[b * 16] = rowptr[b << BSH];
}

// ---------------- phase A: bin edges by dst bucket ----------------
__global__ __launch_bounds__(256) void k_binA(const int* __restrict__ rows,
                                              const int* __restrict__ cols,
                                              int* __restrict__ bucketPtr,
                                              int2* __restrict__ binned) {
  int e = blockIdx.x * 256 + threadIdx.x;
  if (e < NE) {
    int c = cols[e];
    int pos = atomicAdd(&bucketPtr[(c >> BSH) * 16], 1);
    binned[pos] = make_int2(rows[e], c);
  }
}

// ---------------- phase B: within-bucket fill via LDS counters ----------------
// one wave per bucket; bucket edges are binned[rowptr[16b] .. rowptr[16(b+1)])
__global__ __launch_bounds__(64) void k_fillb(const int2* __restrict__ binned,
                                              const int* __restrict__ rowptr,
                                              int* __restrict__ srcIdx) {
  __shared__ int cnt[16];
  int b = blockIdx.x;
  int lane = threadIdx.x;
  if (lane < 16) cnt[lane] = 0;
  __syncthreads();
  int estart = rowptr[b << BSH];
  int eend = (b == NB - 1) ? NE : rowptr[(b + 1) << BSH];
  for (int p = estart + lane; p < eend; p += 64) {
    int2 sd = binned[p];
    int local = atomicAdd(&cnt[sd.y & 15], 1);
    srcIdx[rowptr[sd.y] + local] = sd.x;
  }
}

// ---------------- y = half(x * dinv) ----------------
__global__ __launch_bounds__(256) void k_y(const float4* __restrict__ x4,
                                           const float* __restrict__ dinv,
                                           float2* __restrict__ y8) {
  int gid = blockIdx.x * 256 + threadIdx.x;  // NN*32 float4 units
  if (gid >= NN * 32) return;
  float s = dinv[gid >> 5];
  float4 v = x4[gid];
  union { __half2 h[2]; float2 f; } u;
  u.h[0] = __floats2half2_rn(v.x * s, v.y * s);
  u.h[1] = __floats2half2_rn(v.z * s, v.w * s);
  y8[gid] = u.f;
}

// ---------------- gather-aggregate, width 128 half (wave per node) -----------
__global__ __launch_bounds__(256) void k_gath1(const __half2* __restrict__ y2,
                                               const int* __restrict__ rowptr,
                                               const int* __restrict__ deg,
                                               const int* __restrict__ srcIdx,
                                               const float* __restrict__ dinv,
                                               __half2* __restrict__ agg) {
  int node = blockIdx.x * 4 + (threadIdx.x >> 6);
  int lane = threadIdx.x & 63;
  if (node >= NN) return;
  int d = deg[node];
  int p = rowptr[node];  // start
  size_t rb = (size_t)node * 64 + lane;
  float2 acc = __half22float2(y2[rb]);  // self-loop term
  for (int base = 0; base < d; base += 64) {
    int cnt = min(64, d - base);
    int my = (lane < cnt) ? srcIdx[p + base + lane] : 0;
    int k = 0;
    for (; k + 2 <= cnt; k += 2) {
      int s0 = __shfl(my, k);
      int s1 = __shfl(my, k + 1);
      float2 v0 = __half22float2(y2[(size_t)s0 * 64 + lane]);
      float2 v1 = __half22float2(y2[(size_t)s1 * 64 + lane]);
      acc.x += v0.x + v1.x;
      acc.y += v0.y + v1.y;
    }
    if (k < cnt) {
      int s0 = __shfl(my, k);
      float2 v0 = __half22float2(y2[(size_t)s0 * 64 + lane]);
      acc.x += v0.x;
      acc.y += v0.y;
    }
  }
  float sc = dinv[node];
  agg[rb] = __floats2half2_rn(acc.x * sc, acc.y * sc);
}

// ---------------- gather-aggregate, width 64 half (half-wave per node) -------
__global__ __launch_bounds__(256) void k_gath2(const __half2* __restrict__ z2,
                                               const int* __restrict__ rowptr,
                                               const int* __restrict__ deg,
                                               const int* __restrict__ srcIdx,
                                               const float* __restrict__ dinv,
                                               const float* __restrict__ b2,
                                               float2* __restrict__ out2) {
  int node = blockIdx.x * 8 + (threadIdx.x >> 5);
  int lane = threadIdx.x & 31;
  if (node >= NN) return;
  int d = deg[node];
  int p = rowptr[node];
  float2 acc = __half22float2(z2[(size_t)node * 32 + lane]);
  for (int base = 0; base < d; base += 32) {
    int cnt = min(32, d - base);
    int my = (lane < cnt) ? srcIdx[p + base + lane] : 0;
    int k = 0;
    for (; k + 2 <= cnt; k += 2) {
      int s0 = __shfl(my, k, 32);
      int s1 = __shfl(my, k + 1, 32);
      float2 v0 = __half22float2(z2[(size_t)s0 * 32 + lane]);
      float2 v1 = __half22float2(z2[(size_t)s1 * 32 + lane]);
      acc.x += v0.x + v1.x;
      acc.y += v0.y + v1.y;
    }
    if (k < cnt) {
      int s0 = __shfl(my, k, 32);
      float2 v0 = __half22float2(z2[(size_t)s0 * 32 + lane]);
      acc.x += v0.x;
      acc.y += v0.y;
    }
  }
  float s = dinv[node];
  float2 bv = reinterpret_cast<const float2*>(b2)[lane];
  out2[(size_t)node * 32 + lane] = make_float2(acc.x * s + bv.x, acc.y * s + bv.y);
}

// ---- GEMM: C[M,BN] = A[M,128] @ W[128,BN], A/C half storage, fp32 math ------
template <int BN, bool BIASRELU, bool ROWSCALE>
__global__ __launch_bounds__(256) void k_gemm(const __half2* __restrict__ A2,
                                              const float* __restrict__ W,
                                              const float* __restrict__ bias,
                                              const float* __restrict__ rowscale,
                                              __half* __restrict__ C, int M) {
  constexpr int TN = BN / 16;  // 8 or 4
  __shared__ __align__(16) float xs[32][132];
  __shared__ __align__(16) float ws[32][BN];
  const int tid = threadIdx.x;
  const int tx = tid & 15, ty = tid >> 4;
  const int ry = ty * 8, cx = tx * TN;
  const int rowBase = blockIdx.x * 128;

  float acc[8][TN];
#pragma unroll
  for (int i = 0; i < 8; i++)
#pragma unroll
    for (int j = 0; j < TN; j++) acc[i][j] = 0.0f;

  for (int kc = 0; kc < 128; kc += 32) {
#pragma unroll
    for (int i = tid; i < 32 * BN / 4; i += 256) {
      reinterpret_cast<float4*>(&ws[0][0])[i] =
          reinterpret_cast<const float4*>(W + (size_t)kc * BN)[i];
    }
    // stage A chunk transposed: xs[k][r]; A rows are 64 half2
#pragma unroll
    for (int i = tid; i < 1024; i += 256) {
      int r = i >> 3, j = i & 7;
      int row = rowBase + r;
      float4 v = make_float4(0.f, 0.f, 0.f, 0.f);
      if (row < M) {
        union { float2 f; __half2 h[2]; } u;
        u.f = *reinterpret_cast<const float2*>(A2 + (size_t)row * 64 + (kc >> 1) + 2 * j);
        float2 f0 = __half22float2(u.h[0]);
        float2 f1 = __half22float2(u.h[1]);
        v = make_float4(f0.x, f0.y, f1.x, f1.y);
      }
      xs[4 * j + 0][r] = v.x;
      xs[4 * j + 1][r] = v.y;
      xs[4 * j + 2][r] = v.z;
      xs[4 * j + 3][r] = v.w;
    }
    __syncthreads();
#pragma unroll
    for (int k = 0; k < 32; k++) {
      float4 xa = *reinterpret_cast<const float4*>(&xs[k][ry]);
      float4 xb = *reinterpret_cast<const float4*>(&xs[k][ry + 4]);
      float xv[8] = {xa.x, xa.y, xa.z, xa.w, xb.x, xb.y, xb.z, xb.w};
      float wv[TN];
      float4 wa = *reinterpret_cast<const float4*>(&ws[k][cx]);
      wv[0] = wa.x; wv[1] = wa.y; wv[2] = wa.z; wv[3] = wa.w;
      if constexpr (TN == 8) {
        float4 wb = *reinterpret_cast<const float4*>(&ws[k][cx + 4]);
        wv[4] = wb.x; wv[5] = wb.y; wv[6] = wb.z; wv[7] = wb.w;
      }
#pragma unroll
      for (int i = 0; i < 8; i++)
#pragma unroll
        for (int j = 0; j < TN; j++) acc[i][j] += xv[i] * wv[j];
    }
    __syncthreads();
  }

#pragma unroll
  for (int i = 0; i < 8; i++) {
    int row = rowBase + ry + i;
    if (row < M) {
      float rs = ROWSCALE ? rowscale[row] : 1.0f;
      float vals[TN];
#pragma unroll
      for (int j = 0; j < TN; j++) {
        float v = acc[i][j];
        if constexpr (BIASRELU) v = fmaxf(v + bias[cx + j], 0.f);
        if constexpr (ROWSCALE) v *= rs;
        vals[j] = v;
      }
      __half* cp = C + (size_t)row * BN + cx;
      if constexpr (TN == 8) {
        union { __half2 h[4]; float4 f; } u;
        u.h[0] = __floats2half2_rn(vals[0], vals[1]);
        u.h[1] = __floats2half2_rn(vals[2], vals[3]);
        u.h[2] = __floats2half2_rn(vals[4], vals[5]);
        u.h[3] = __floats2half2_rn(vals[6], vals[7]);
        *reinterpret_cast<float4*>(cp) = u.f;
      } else {
        union { __half2 h[2]; float2 f; } u;
        u.h[0] = __floats2half2_rn(vals[0], vals[1]);
        u.h[1] = __floats2half2_rn(vals[2], vals[3]);
        *reinterpret_cast<float2*>(cp) = u.f;
      }
    }
  }
}

extern "C" void kernel_launch(void* const* d_in, const int* in_sizes, int n_in,
                              void* d_out, int out_size, void* d_ws, size_t ws_size,
                              hipStream_t stream) {
  const float* x  = (const float*)d_in[0];
  const int*   ei = (const int*)d_in[1];  // [2, NE] row-major
  const int* rows = ei;
  const int* cols = ei + NE;
  const float* W1 = (const float*)d_in[3];
  const float* b1 = (const float*)d_in[4];
  const float* W2 = (const float*)d_in[5];
  const float* b2 = (const float*)d_in[6];
  float* out = (float*)d_out;

  // ---- workspace carve (~103 MB) ----
  char* base = (char*)d_ws;
  constexpr size_t MB = 1 << 20;
  int*     deg       = (int*)(base + 0 * MB);
  int*     rowptr    = (int*)(base + 1 * MB);       // start pointers (pristine)
  float*   dinv      = (float*)(base + 2 * MB);
  int*     blockSum  = (int*)(base + 3 * MB);
  int*     blockOff  = (int*)(base + 3 * MB + 4096);
  int*     bucketPtr = (int*)(base + 4 * MB);       // 400 KB (64B-padded counters)
  int*     srcIdx    = (int*)(base + 5 * MB);       // 6.4 MB
  int2*    binned    = (int2*)(base + 12 * MB);     // 12.8 MB
  __half2* y         = (__half2*)(base + 25 * MB);  // 25.6 MB (reused for z)
  __half*  aggx      = (__half*)(base + 51 * MB);   // 25.6 MB
  __half*  h1        = (__half*)(base + 77 * MB);   // 25.6 MB
  __half2* z         = (__half2*)(base + 25 * MB);  // 12.8 MB (y dead)

  constexpr int SCAN_BLOCKS = (NN + 1023) / 1024;  // 98

  hipMemsetAsync(deg, 0, NN * sizeof(int), stream);
  k_deg<<<(NE + 255) / 256, 256, 0, stream>>>(cols, deg);
  k_scanA<<<SCAN_BLOCKS, 256, 0, stream>>>(deg, rowptr, blockSum);
  k_scanB<<<1, 128, 0, stream>>>(blockSum, blockOff, SCAN_BLOCKS);
  k_scanC<<<(NN + 255) / 256, 256, 0, stream>>>(rowptr, blockOff, deg, dinv);
  k_binit<<<(NB + 255) / 256, 256, 0, stream>>>(rowptr, bucketPtr);
  k_binA<<<(NE + 255) / 256, 256, 0, stream>>>(rows, cols, bucketPtr, binned);
  k_fillb<<<NB, 64, 0, stream>>>(binned, rowptr, srcIdx);
  k_y<<<(NN * 32 + 255) / 256, 256, 0, stream>>>((const float4*)x, dinv, (float2*)y);
  k_gath1<<<(NN + 3) / 4, 256, 0, stream>>>(y, rowptr, deg, srcIdx, dinv,
                                            (__half2*)aggx);
  k_gemm<128, true, false><<<(NN + 127) / 128, 256, 0, stream>>>(
      (const __half2*)aggx, W1, b1, nullptr, h1, NN);
  k_gemm<64, false, true><<<(NN + 127) / 128, 256, 0, stream>>>(
      (const __half2*)h1, W2, nullptr, dinv, (__half*)z, NN);
  k_gath2<<<(NN + 7) / 8, 256, 0, stream>>>(z, rowptr, deg, srcIdx, dinv, b2,
                                            (float2*)out);
}

// Round 6
// 440.715 us; speedup vs baseline: 1.1582x; 1.1582x over previous
//
#include <hip/hip_runtime.h>
#include <hip/hip_fp16.h>

// GCN 2-layer, CSR-gather formulation, fp16 storage / fp32 math.
//   y = half(x * dinv)
//   aggX[c] = half( dinv[c] * (y[c] + sum_{r in in(c)} y[r]) )
//   h1 = half( relu(aggX @ W1 + b1) )
//   z  = half( (h1 @ W2) * dinv )
//   out[c] = fp32( dinv[c] * (z[c] + sum z[r]) + b2 )
// CSR build: deterministic 2-pass binning (per-block bucket histogram + column
// scan -> exclusive (block,bucket) ranges -> LDS-counter scatter), then a
// per-bucket fill pass (one block owns each bucket's contiguous srcIdx range).
// No global atomics claim scatter slots: round-4 lesson is that global-atomic
// slot claiming interleaves XCDs within each 64B line, so every 8B store
// becomes a partial-line HBM write (93 MB for 12.8 MB of data).

constexpr int NN = 100000;   // nodes
constexpr int NE = 1600000;  // edges
constexpr int BSH = 7;       // 128 nodes per bucket
constexpr int NB = (NN + 127) >> BSH;  // 782 buckets
constexpr int NBLK = 256;    // binning blocks
constexpr int EPB = NE / NBLK;  // 6250 edges per block (exact)
constexpr int TSTR = 784;    // table row stride (ints)

// ------------- degree histogram + per-(block,bucket) histogram ---------------
__global__ __launch_bounds__(256) void k_deg(const int* __restrict__ cols,
                                             int* __restrict__ deg,
                                             int* __restrict__ table) {
  __shared__ int cnt[NB];
  for (int i = threadIdx.x; i < NB; i += 256) cnt[i] = 0;
  __syncthreads();
  int base = blockIdx.x * EPB;
  for (int i = threadIdx.x; i < EPB; i += 256) {
    int c = cols[base + i];
    atomicAdd(&deg[c], 1);
    atomicAdd(&cnt[c >> BSH], 1);
  }
  __syncthreads();
  for (int i = threadIdx.x; i < NB; i += 256)
    table[blockIdx.x * TSTR + i] = cnt[i];
}

// ---------------- exclusive scan of deg -> rowptr (3 kernels) ----------------
__global__ __launch_bounds__(256) void k_scanA(const int* __restrict__ deg,
                                               int* __restrict__ rowptr,
                                               int* __restrict__ blockSum) {
  __shared__ int s[256];
  int t = threadIdx.x, b = blockIdx.x;
  int base = b * 1024 + t * 4;
  int d0 = (base + 0 < NN) ? deg[base + 0] : 0;
  int d1 = (base + 1 < NN) ? deg[base + 1] : 0;
  int d2 = (base + 2 < NN) ? deg[base + 2] : 0;
  int d3 = (base + 3 < NN) ? deg[base + 3] : 0;
  int tsum = d0 + d1 + d2 + d3;
  s[t] = tsum;
  __syncthreads();
  for (int off = 1; off < 256; off <<= 1) {
    int tmp = (t >= off) ? s[t - off] : 0;
    __syncthreads();
    s[t] += tmp;
    __syncthreads();
  }
  int ex = s[t] - tsum;
  if (base + 0 < NN) rowptr[base + 0] = ex;
  if (base + 1 < NN) rowptr[base + 1] = ex + d0;
  if (base + 2 < NN) rowptr[base + 2] = ex + d0 + d1;
  if (base + 3 < NN) rowptr[base + 3] = ex + d0 + d1 + d2;
  if (t == 255) blockSum[b] = ex + tsum;
}

__global__ __launch_bounds__(128) void k_scanB(int* __restrict__ blockSum,
                                               int* __restrict__ blockOff,
                                               int nblocks) {
  __shared__ int s[128];
  int t = threadIdx.x;
  int v = (t < nblocks) ? blockSum[t] : 0;
  s[t] = v;
  __syncthreads();
  for (int off = 1; off < 128; off <<= 1) {
    int tmp = (t >= off) ? s[t - off] : 0;
    __syncthreads();
    s[t] += tmp;
    __syncthreads();
  }
  if (t < nblocks) blockOff[t] = s[t] - v;
}

__global__ __launch_bounds__(256) void k_scanC(int* __restrict__ rowptr,
                                               const int* __restrict__ blockOff,
                                               const int* __restrict__ deg,
                                               float* __restrict__ dinv) {
  int i = blockIdx.x * 256 + threadIdx.x;
  if (i < NN) {
    rowptr[i] += blockOff[i >> 10];
    dinv[i] = rsqrtf((float)deg[i] + 1.0f);
  }
}

// ------- scan table columns: start[blk][b] = rowptr[b<<BSH] + sum_{<blk} -----
__global__ __launch_bounds__(256) void k_scanT(const int* __restrict__ table,
                                               const int* __restrict__ rowptr,
                                               int* __restrict__ start) {
  __shared__ int s[256];
  int b = blockIdx.x, t = threadIdx.x;
  int v = table[t * TSTR + b];
  s[t] = v;
  __syncthreads();
  for (int off = 1; off < 256; off <<= 1) {
    int tmp = (t >= off) ? s[t - off] : 0;
    __syncthreads();
    s[t] += tmp;
    __syncthreads();
  }
  int ex = s[t] - v;
  start[t * TSTR + b] = rowptr[b << BSH] + ex;
}

// ------- scatter edges into bucket-grouped array (LDS counters only) ---------
__global__ __launch_bounds__(256) void k_scat(const int* __restrict__ rows,
                                              const int* __restrict__ cols,
                                              const int* __restrict__ start,
                                              unsigned* __restrict__ binned) {
  __shared__ int scnt[NB];
  int blk = blockIdx.x;
  for (int i = threadIdx.x; i < NB; i += 256) scnt[i] = start[blk * TSTR + i];
  __syncthreads();
  int base = blk * EPB;
  for (int i = threadIdx.x; i < EPB; i += 256) {
    int c = cols[base + i];
    int r = rows[base + i];
    int pos = atomicAdd(&scnt[c >> BSH], 1);
    binned[pos] = ((unsigned)r << BSH) | (unsigned)(c & 127);
  }
}

// ------- per-bucket fill: bucket-grouped packed edges -> node-grouped srcIdx -
// one block per bucket; block exclusively owns srcIdx[rowptr[nb0]..eend)
__global__ __launch_bounds__(256) void k_fillb(const unsigned* __restrict__ binned,
                                               const int* __restrict__ rowptr,
                                               int* __restrict__ srcIdx) {
  __shared__ int rp[128];
  __shared__ int cnt[128];
  int b = blockIdx.x;
  int nb0 = b << BSH;
  int nn = min(128, NN - nb0);
  if (threadIdx.x < 128) {
    cnt[threadIdx.x] = 0;
    rp[threadIdx.x] = (threadIdx.x < nn) ? rowptr[nb0 + threadIdx.x] : 0;
  }
  __syncthreads();
  int ebeg = rowptr[nb0];
  int eend = (b == NB - 1) ? NE : rowptr[nb0 + 128];
  for (int p = ebeg + (int)threadIdx.x; p < eend; p += 256) {
    unsigned pk = binned[p];
    int cl = pk & 127;
    int local = atomicAdd(&cnt[cl], 1);
    srcIdx[rp[cl] + local] = (int)(pk >> BSH);
  }
}

// ---------------- y = half(x * dinv) ----------------
__global__ __launch_bounds__(256) void k_y(const float4* __restrict__ x4,
                                           const float* __restrict__ dinv,
                                           float2* __restrict__ y8) {
  int gid = blockIdx.x * 256 + threadIdx.x;  // NN*32 float4 units
  if (gid >= NN * 32) return;
  float s = dinv[gid >> 5];
  float4 v = x4[gid];
  union { __half2 h[2]; float2 f; } u;
  u.h[0] = __floats2half2_rn(v.x * s, v.y * s);
  u.h[1] = __floats2half2_rn(v.z * s, v.w * s);
  y8[gid] = u.f;
}

// ---------------- gather-aggregate, width 128 half (wave per node) -----------
__global__ __launch_bounds__(256) void k_gath1(const __half2* __restrict__ y2,
                                               const int* __restrict__ rowptr,
                                               const int* __restrict__ deg,
                                               const int* __restrict__ srcIdx,
                                               const float* __restrict__ dinv,
                                               __half2* __restrict__ agg) {
  int node = blockIdx.x * 4 + (threadIdx.x >> 6);
  int lane = threadIdx.x & 63;
  if (node >= NN) return;
  int d = deg[node];
  int p = rowptr[node];  // start
  size_t rb = (size_t)node * 64 + lane;
  float2 acc = __half22float2(y2[rb]);  // self-loop term
  for (int base = 0; base < d; base += 64) {
    int cnt = min(64, d - base);
    int my = (lane < cnt) ? srcIdx[p + base + lane] : 0;
    int k = 0;
    for (; k + 2 <= cnt; k += 2) {
      int s0 = __shfl(my, k);
      int s1 = __shfl(my, k + 1);
      float2 v0 = __half22float2(y2[(size_t)s0 * 64 + lane]);
      float2 v1 = __half22float2(y2[(size_t)s1 * 64 + lane]);
      acc.x += v0.x + v1.x;
      acc.y += v0.y + v1.y;
    }
    if (k < cnt) {
      int s0 = __shfl(my, k);
      float2 v0 = __half22float2(y2[(size_t)s0 * 64 + lane]);
      acc.x += v0.x;
      acc.y += v0.y;
    }
  }
  float sc = dinv[node];
  agg[rb] = __floats2half2_rn(acc.x * sc, acc.y * sc);
}

// ---------------- gather-aggregate, width 64 half (half-wave per node) -------
__global__ __launch_bounds__(256) void k_gath2(const __half2* __restrict__ z2,
                                               const int* __restrict__ rowptr,
                                               const int* __restrict__ deg,
                                               const int* __restrict__ srcIdx,
                                               const float* __restrict__ dinv,
                                               const float* __restrict__ b2,
                                               float2* __restrict__ out2) {
  int node = blockIdx.x * 8 + (threadIdx.x >> 5);
  int lane = threadIdx.x & 31;
  if (node >= NN) return;
  int d = deg[node];
  int p = rowptr[node];
  float2 acc = __half22float2(z2[(size_t)node * 32 + lane]);
  for (int base = 0; base < d; base += 32) {
    int cnt = min(32, d - base);
    int my = (lane < cnt) ? srcIdx[p + base + lane] : 0;
    int k = 0;
    for (; k + 2 <= cnt; k += 2) {
      int s0 = __shfl(my, k, 32);
      int s1 = __shfl(my, k + 1, 32);
      float2 v0 = __half22float2(z2[(size_t)s0 * 32 + lane]);
      float2 v1 = __half22float2(z2[(size_t)s1 * 32 + lane]);
      acc.x += v0.x + v1.x;
      acc.y += v0.y + v1.y;
    }
    if (k < cnt) {
      int s0 = __shfl(my, k, 32);
      float2 v0 = __half22float2(z2[(size_t)s0 * 32 + lane]);
      acc.x += v0.x;
      acc.y += v0.y;
    }
  }
  float s = dinv[node];
  float2 bv = reinterpret_cast<const float2*>(b2)[lane];
  out2[(size_t)node * 32 + lane] = make_float2(acc.x * s + bv.x, acc.y * s + bv.y);
}

// ---- GEMM: C[M,BN] = A[M,128] @ W[128,BN], A/C half storage, fp32 math ------
template <int BN, bool BIASRELU, bool ROWSCALE>
__global__ __launch_bounds__(256) void k_gemm(const __half2* __restrict__ A2,
                                              const float* __restrict__ W,
                                              const float* __restrict__ bias,
                                              const float* __restrict__ rowscale,
                                              __half* __restrict__ C, int M) {
  constexpr int TN = BN / 16;  // 8 or 4
  __shared__ __align__(16) float xs[32][132];
  __shared__ __align__(16) float ws[32][BN];
  const int tid = threadIdx.x;
  const int tx = tid & 15, ty = tid >> 4;
  const int ry = ty * 8, cx = tx * TN;
  const int rowBase = blockIdx.x * 128;

  float acc[8][TN];
#pragma unroll
  for (int i = 0; i < 8; i++)
#pragma unroll
    for (int j = 0; j < TN; j++) acc[i][j] = 0.0f;

  for (int kc = 0; kc < 128; kc += 32) {
#pragma unroll
    for (int i = tid; i < 32 * BN / 4; i += 256) {
      reinterpret_cast<float4*>(&ws[0][0])[i] =
          reinterpret_cast<const float4*>(W + (size_t)kc * BN)[i];
    }
#pragma unroll
    for (int i = tid; i < 1024; i += 256) {
      int r = i >> 3, j = i & 7;
      int row = rowBase + r;
      float4 v = make_float4(0.f, 0.f, 0.f, 0.f);
      if (row < M) {
        union { float2 f; __half2 h[2]; } u;
        u.f = *reinterpret_cast<const float2*>(A2 + (size_t)row * 64 + (kc >> 1) + 2 * j);
        float2 f0 = __half22float2(u.h[0]);
        float2 f1 = __half22float2(u.h[1]);
        v = make_float4(f0.x, f0.y, f1.x, f1.y);
      }
      xs[4 * j + 0][r] = v.x;
      xs[4 * j + 1][r] = v.y;
      xs[4 * j + 2][r] = v.z;
      xs[4 * j + 3][r] = v.w;
    }
    __syncthreads();
#pragma unroll
    for (int k = 0; k < 32; k++) {
      float4 xa = *reinterpret_cast<const float4*>(&xs[k][ry]);
      float4 xb = *reinterpret_cast<const float4*>(&xs[k][ry + 4]);
      float xv[8] = {xa.x, xa.y, xa.z, xa.w, xb.x, xb.y, xb.z, xb.w};
      float wv[TN];
      float4 wa = *reinterpret_cast<const float4*>(&ws[k][cx]);
      wv[0] = wa.x; wv[1] = wa.y; wv[2] = wa.z; wv[3] = wa.w;
      if constexpr (TN == 8) {
        float4 wb = *reinterpret_cast<const float4*>(&ws[k][cx + 4]);
        wv[4] = wb.x; wv[5] = wb.y; wv[6] = wb.z; wv[7] = wb.w;
      }
#pragma unroll
      for (int i = 0; i < 8; i++)
#pragma unroll
        for (int j = 0; j < TN; j++) acc[i][j] += xv[i] * wv[j];
    }
    __syncthreads();
  }

#pragma unroll
  for (int i = 0; i < 8; i++) {
    int row = rowBase + ry + i;
    if (row < M) {
      float rs = ROWSCALE ? rowscale[row] : 1.0f;
      float vals[TN];
#pragma unroll
      for (int j = 0; j < TN; j++) {
        float v = acc[i][j];
        if constexpr (BIASRELU) v = fmaxf(v + bias[cx + j], 0.f);
        if constexpr (ROWSCALE) v *= rs;
        vals[j] = v;
      }
      __half* cp = C + (size_t)row * BN + cx;
      if constexpr (TN == 8) {
        union { __half2 h[4]; float4 f; } u;
        u.h[0] = __floats2half2_rn(vals[0], vals[1]);
        u.h[1] = __floats2half2_rn(vals[2], vals[3]);
        u.h[2] = __floats2half2_rn(vals[4], vals[5]);
        u.h[3] = __floats2half2_rn(vals[6], vals[7]);
        *reinterpret_cast<float4*>(cp) = u.f;
      } else {
        union { __half2 h[2]; float2 f; } u;
        u.h[0] = __floats2half2_rn(vals[0], vals[1]);
        u.h[1] = __floats2half2_rn(vals[2], vals[3]);
        *reinterpret_cast<float2*>(cp) = u.f;
      }
    }
  }
}

extern "C" void kernel_launch(void* const* d_in, const int* in_sizes, int n_in,
                              void* d_out, int out_size, void* d_ws, size_t ws_size,
                              hipStream_t stream) {
  const float* x  = (const float*)d_in[0];
  const int*   ei = (const int*)d_in[1];  // [2, NE] row-major
  const int* rows = ei;
  const int* cols = ei + NE;
  const float* W1 = (const float*)d_in[3];
  const float* b1 = (const float*)d_in[4];
  const float* W2 = (const float*)d_in[5];
  const float* b2 = (const float*)d_in[6];
  float* out = (float*)d_out;

  // ---- workspace carve (~90 MB) ----
  char* base = (char*)d_ws;
  constexpr size_t MB = 1 << 20;
  int*      deg      = (int*)(base + 0 * MB);
  int*      rowptr   = (int*)(base + 1 * MB);   // start pointers (never mutated)
  float*    dinv     = (float*)(base + 2 * MB);
  int*      blockSum = (int*)(base + 3 * MB);
  int*      blockOff = (int*)(base + 3 * MB + 4096);
  int*      table    = (int*)(base + 4 * MB);   // 803 KB
  int*      start    = (int*)(base + 5 * MB);   // 803 KB
  unsigned* binned   = (unsigned*)(base + 6 * MB);   // 6.4 MB
  int*      srcIdx   = (int*)(base + 13 * MB);       // 6.4 MB
  __half2*  y        = (__half2*)(base + 20 * MB);   // 25.6 MB (reused for z)
  __half*   aggx     = (__half*)(base + 46 * MB);    // 25.6 MB
  __half*   h1       = (__half*)(base + 72 * MB);    // 25.6 MB
  __half2*  z        = (__half2*)(base + 20 * MB);   // 12.8 MB (y dead)

  constexpr int SCAN_BLOCKS = (NN + 1023) / 1024;  // 98

  hipMemsetAsync(deg, 0, NN * sizeof(int), stream);
  k_deg<<<NBLK, 256, 0, stream>>>(cols, deg, table);
  k_scanA<<<SCAN_BLOCKS, 256, 0, stream>>>(deg, rowptr, blockSum);
  k_scanB<<<1, 128, 0, stream>>>(blockSum, blockOff, SCAN_BLOCKS);
  k_scanC<<<(NN + 255) / 256, 256, 0, stream>>>(rowptr, blockOff, deg, dinv);
  k_scanT<<<NB, 256, 0, stream>>>(table, rowptr, start);
  k_scat<<<NBLK, 256, 0, stream>>>(rows, cols, start, binned);
  k_fillb<<<NB, 256, 0, stream>>>(binned, rowptr, srcIdx);
  k_y<<<(NN * 32 + 255) / 256, 256, 0, stream>>>((const float4*)x, dinv, (float2*)y);
  k_gath1<<<(NN + 3) / 4, 256, 0, stream>>>(y, rowptr, deg, srcIdx, dinv,
                                            (__half2*)aggx);
  k_gemm<128, true, false><<<(NN + 127) / 128, 256, 0, stream>>>(
      (const __half2*)aggx, W1, b1, nullptr, h1, NN);
  k_gemm<64, false, true><<<(NN + 127) / 128, 256, 0, stream>>>(
      (const __half2*)h1, W2, nullptr, dinv, (__half*)z, NN);
  k_gath2<<<(NN + 7) / 8, 256, 0, stream>>>(z, rowptr, deg, srcIdx, dinv, b2,
                                            (float2*)out);
}

// Round 7
// 385.245 us; speedup vs baseline: 1.3249x; 1.1440x over previous
//
#include <hip/hip_runtime.h>
#include <hip/hip_fp16.h>

// GCN 2-layer, CSR-gather formulation, fp16 storage / fp32 math, MFMA GEMMs.
//   y = half(x * dinv)
//   aggX[c] = half( dinv[c] * (y[c] + sum_{r in in(c)} y[r]) )
//   h1 = half( relu(aggX @ W1 + b1) )          [MFMA f16, fp32 acc]
//   z  = half( (h1 @ W2) * dinv )              [MFMA f16, fp32 acc]
//   out[c] = fp32( dinv[c] * (z[c] + sum z[r]) + b2 )
// CSR build: deterministic 2-pass binning (per-block bucket histogram + column
// scan -> exclusive (block,bucket) ranges -> LDS-counter scatter), then a
// per-bucket fill pass. No global-atomic slot claiming (round-4 lesson: it
// interleaves XCDs within 64B lines -> every store becomes a partial-line
// HBM write).

constexpr int NN = 100000;   // nodes
constexpr int NE = 1600000;  // edges
constexpr int BSH = 7;       // 128 nodes per bucket
constexpr int NB = (NN + 127) >> BSH;  // 782 buckets
constexpr int NBLK = 256;    // binning blocks
constexpr int EPB = NE / NBLK;  // 6250 edges per block (exact)
constexpr int TSTR = 784;    // table row stride (ints)

typedef _Float16 f16x8 __attribute__((ext_vector_type(8)));
typedef float f32x4 __attribute__((ext_vector_type(4)));

// ------------- degree histogram + per-(block,bucket) histogram ---------------
__global__ __launch_bounds__(256) void k_deg(const int* __restrict__ cols,
                                             int* __restrict__ deg,
                                             int* __restrict__ table) {
  __shared__ int cnt[NB];
  for (int i = threadIdx.x; i < NB; i += 256) cnt[i] = 0;
  __syncthreads();
  int base = blockIdx.x * EPB;
  for (int i = threadIdx.x; i < EPB; i += 256) {
    int c = cols[base + i];
    atomicAdd(&deg[c], 1);
    atomicAdd(&cnt[c >> BSH], 1);
  }
  __syncthreads();
  for (int i = threadIdx.x; i < NB; i += 256)
    table[blockIdx.x * TSTR + i] = cnt[i];
}

// ---------------- exclusive scan of deg -> rowptr (3 kernels) ----------------
__global__ __launch_bounds__(256) void k_scanA(const int* __restrict__ deg,
                                               int* __restrict__ rowptr,
                                               int* __restrict__ blockSum) {
  __shared__ int s[256];
  int t = threadIdx.x, b = blockIdx.x;
  int base = b * 1024 + t * 4;
  int d0 = (base + 0 < NN) ? deg[base + 0] : 0;
  int d1 = (base + 1 < NN) ? deg[base + 1] : 0;
  int d2 = (base + 2 < NN) ? deg[base + 2] : 0;
  int d3 = (base + 3 < NN) ? deg[base + 3] : 0;
  int tsum = d0 + d1 + d2 + d3;
  s[t] = tsum;
  __syncthreads();
  for (int off = 1; off < 256; off <<= 1) {
    int tmp = (t >= off) ? s[t - off] : 0;
    __syncthreads();
    s[t] += tmp;
    __syncthreads();
  }
  int ex = s[t] - tsum;
  if (base + 0 < NN) rowptr[base + 0] = ex;
  if (base + 1 < NN) rowptr[base + 1] = ex + d0;
  if (base + 2 < NN) rowptr[base + 2] = ex + d0 + d1;
  if (base + 3 < NN) rowptr[base + 3] = ex + d0 + d1 + d2;
  if (t == 255) blockSum[b] = ex + tsum;
}

__global__ __launch_bounds__(128) void k_scanB(int* __restrict__ blockSum,
                                               int* __restrict__ blockOff,
                                               int nblocks) {
  __shared__ int s[128];
  int t = threadIdx.x;
  int v = (t < nblocks) ? blockSum[t] : 0;
  s[t] = v;
  __syncthreads();
  for (int off = 1; off < 128; off <<= 1) {
    int tmp = (t >= off) ? s[t - off] : 0;
    __syncthreads();
    s[t] += tmp;
    __syncthreads();
  }
  if (t < nblocks) blockOff[t] = s[t] - v;
}

__global__ __launch_bounds__(256) void k_scanC(int* __restrict__ rowptr,
                                               const int* __restrict__ blockOff,
                                               const int* __restrict__ deg,
                                               float* __restrict__ dinv) {
  int i = blockIdx.x * 256 + threadIdx.x;
  if (i < NN) {
    rowptr[i] += blockOff[i >> 10];
    dinv[i] = rsqrtf((float)deg[i] + 1.0f);
  }
}

// ------- scan table columns: start[blk][b] = rowptr[b<<BSH] + sum_{<blk} -----
__global__ __launch_bounds__(256) void k_scanT(const int* __restrict__ table,
                                               const int* __restrict__ rowptr,
                                               int* __restrict__ start) {
  __shared__ int s[256];
  int b = blockIdx.x, t = threadIdx.x;
  int v = table[t * TSTR + b];
  s[t] = v;
  __syncthreads();
  for (int off = 1; off < 256; off <<= 1) {
    int tmp = (t >= off) ? s[t - off] : 0;
    __syncthreads();
    s[t] += tmp;
    __syncthreads();
  }
  int ex = s[t] - v;
  start[t * TSTR + b] = rowptr[b << BSH] + ex;
}

// ------- scatter edges into bucket-grouped array (LDS counters only) ---------
__global__ __launch_bounds__(256) void k_scat(const int* __restrict__ rows,
                                              const int* __restrict__ cols,
                                              const int* __restrict__ start,
                                              unsigned* __restrict__ binned) {
  __shared__ int scnt[NB];
  int blk = blockIdx.x;
  for (int i = threadIdx.x; i < NB; i += 256) scnt[i] = start[blk * TSTR + i];
  __syncthreads();
  int base = blk * EPB;
  for (int i = threadIdx.x; i < EPB; i += 256) {
    int c = cols[base + i];
    int r = rows[base + i];
    int pos = atomicAdd(&scnt[c >> BSH], 1);
    binned[pos] = ((unsigned)r << BSH) | (unsigned)(c & 127);
  }
}

// ------- per-bucket fill: bucket-grouped packed edges -> node-grouped srcIdx -
__global__ __launch_bounds__(256) void k_fillb(const unsigned* __restrict__ binned,
                                               const int* __restrict__ rowptr,
                                               int* __restrict__ srcIdx) {
  __shared__ int rp[128];
  __shared__ int cnt[128];
  int b = blockIdx.x;
  int nb0 = b << BSH;
  int nn = min(128, NN - nb0);
  if (threadIdx.x < 128) {
    cnt[threadIdx.x] = 0;
    rp[threadIdx.x] = (threadIdx.x < nn) ? rowptr[nb0 + threadIdx.x] : 0;
  }
  __syncthreads();
  int ebeg = rowptr[nb0];
  int eend = (b == NB - 1) ? NE : rowptr[nb0 + 128];
  for (int p = ebeg + (int)threadIdx.x; p < eend; p += 256) {
    unsigned pk = binned[p];
    int cl = pk & 127;
    int local = atomicAdd(&cnt[cl], 1);
    srcIdx[rp[cl] + local] = (int)(pk >> BSH);
  }
}

// ------------- weight convert+transpose: W [K][N] f32 -> Wt [N][K] f16 -------
__global__ __launch_bounds__(256) void k_wt(const float* __restrict__ W,
                                            __half* __restrict__ Wt, int K, int N) {
  int i = blockIdx.x * 256 + threadIdx.x;
  if (i < K * N) {
    int k = i / N, n = i % N;
    Wt[n * K + k] = __float2half(W[i]);
  }
}

// ---------------- y = half(x * dinv) ----------------
__global__ __launch_bounds__(256) void k_y(const float4* __restrict__ x4,
                                           const float* __restrict__ dinv,
                                           float2* __restrict__ y8) {
  int gid = blockIdx.x * 256 + threadIdx.x;  // NN*32 float4 units
  if (gid >= NN * 32) return;
  float s = dinv[gid >> 5];
  float4 v = x4[gid];
  union { __half2 h[2]; float2 f; } u;
  u.h[0] = __floats2half2_rn(v.x * s, v.y * s);
  u.h[1] = __floats2half2_rn(v.z * s, v.w * s);
  y8[gid] = u.f;
}

// ---------------- gather-aggregate, width 128 half (wave per node) -----------
__global__ __launch_bounds__(256) void k_gath1(const __half2* __restrict__ y2,
                                               const int* __restrict__ rowptr,
                                               const int* __restrict__ deg,
                                               const int* __restrict__ srcIdx,
                                               const float* __restrict__ dinv,
                                               __half2* __restrict__ agg) {
  int node = blockIdx.x * 4 + (threadIdx.x >> 6);
  int lane = threadIdx.x & 63;
  if (node >= NN) return;
  int d = deg[node];
  int p = rowptr[node];  // start
  size_t rb = (size_t)node * 64 + lane;
  float2 acc = __half22float2(y2[rb]);  // self-loop term
  for (int base = 0; base < d; base += 64) {
    int cnt = min(64, d - base);
    int my = (lane < cnt) ? srcIdx[p + base + lane] : 0;
    int k = 0;
    for (; k + 4 <= cnt; k += 4) {
      int s0 = __shfl(my, k);
      int s1 = __shfl(my, k + 1);
      int s2 = __shfl(my, k + 2);
      int s3 = __shfl(my, k + 3);
      float2 v0 = __half22float2(y2[(size_t)s0 * 64 + lane]);
      float2 v1 = __half22float2(y2[(size_t)s1 * 64 + lane]);
      float2 v2 = __half22float2(y2[(size_t)s2 * 64 + lane]);
      float2 v3 = __half22float2(y2[(size_t)s3 * 64 + lane]);
      acc.x += v0.x + v1.x + v2.x + v3.x;
      acc.y += v0.y + v1.y + v2.y + v3.y;
    }
    for (; k < cnt; k++) {
      int s0 = __shfl(my, k);
      float2 v0 = __half22float2(y2[(size_t)s0 * 64 + lane]);
      acc.x += v0.x;
      acc.y += v0.y;
    }
  }
  float sc = dinv[node];
  agg[rb] = __floats2half2_rn(acc.x * sc, acc.y * sc);
}

// ---------------- gather-aggregate, width 64 half (half-wave per node) -------
__global__ __launch_bounds__(256) void k_gath2(const __half2* __restrict__ z2,
                                               const int* __restrict__ rowptr,
                                               const int* __restrict__ deg,
                                               const int* __restrict__ srcIdx,
                                               const float* __restrict__ dinv,
                                               const float* __restrict__ b2,
                                               float2* __restrict__ out2) {
  int node = blockIdx.x * 8 + (threadIdx.x >> 5);
  int lane = threadIdx.x & 31;
  if (node >= NN) return;
  int d = deg[node];
  int p = rowptr[node];
  float2 acc = __half22float2(z2[(size_t)node * 32 + lane]);
  for (int base = 0; base < d; base += 32) {
    int cnt = min(32, d - base);
    int my = (lane < cnt) ? srcIdx[p + base + lane] : 0;
    int k = 0;
    for (; k + 4 <= cnt; k += 4) {
      int s0 = __shfl(my, k, 32);
      int s1 = __shfl(my, k + 1, 32);
      int s2 = __shfl(my, k + 2, 32);
      int s3 = __shfl(my, k + 3, 32);
      float2 v0 = __half22float2(z2[(size_t)s0 * 32 + lane]);
      float2 v1 = __half22float2(z2[(size_t)s1 * 32 + lane]);
      float2 v2 = __half22float2(z2[(size_t)s2 * 32 + lane]);
      float2 v3 = __half22float2(z2[(size_t)s3 * 32 + lane]);
      acc.x += v0.x + v1.x + v2.x + v3.x;
      acc.y += v0.y + v1.y + v2.y + v3.y;
    }
    for (; k < cnt; k++) {
      int s0 = __shfl(my, k, 32);
      float2 v0 = __half22float2(z2[(size_t)s0 * 32 + lane]);
      acc.x += v0.x;
      acc.y += v0.y;
    }
  }
  float s = dinv[node];
  float2 bv = reinterpret_cast<const float2*>(b2)[lane];
  out2[(size_t)node * 32 + lane] = make_float2(acc.x * s + bv.x, acc.y * s + bv.y);
}

// ---- MFMA GEMM: C[M,BN] = A[M,128] @ W[128,BN], f16 in, fp32 acc, f16 out ---
// A fragment: lane holds A[row = rowTop + (l&15)][kc + (l>>4)*8 + j], j=0..7
// B fragment: lane holds W[kc + (l>>4)*8 + j][col = ct*16 + (l&15)]
//             = Wt[col][kc + quad*8 + j] with Wt in [N][K] f16 layout
// C/D:        lane reg i = C[rowTop + (l>>4)*4 + i][ct*16 + (l&15)]  (m89)
template <int BN, bool BIASRELU, bool ROWSCALE>
__global__ __launch_bounds__(256) void k_gemmM(const __half* __restrict__ A,
                                               const __half* __restrict__ Wt,
                                               const float* __restrict__ bias,
                                               const float* __restrict__ rowscale,
                                               __half* __restrict__ C, int M) {
  constexpr int NT = BN / 16;  // 8 or 4 col tiles per wave
  __shared__ __half tile[4][16][BN + 8];  // +8 pad: breaks 4-quad bank overlap
  const int w = threadIdx.x >> 6, l = threadIdx.x & 63;
  const int quad = l >> 4, m = l & 15;
  const int rowTop = blockIdx.x * 64 + w * 16;

  f32x4 acc[NT];
#pragma unroll
  for (int t = 0; t < NT; t++) {
    float bv = BIASRELU ? bias[t * 16 + m] : 0.0f;
    acc[t] = (f32x4){bv, bv, bv, bv};
  }

  int arow = rowTop + m;
  if (arow >= M) arow = M - 1;  // clamp: garbage rows computed but not stored
  const __half* ap = A + (size_t)arow * 128 + quad * 8;

#pragma unroll
  for (int kc = 0; kc < 128; kc += 32) {
    f16x8 a = *reinterpret_cast<const f16x8*>(ap + kc);
#pragma unroll
    for (int t = 0; t < NT; t++) {
      f16x8 b = *reinterpret_cast<const f16x8*>(
          Wt + (size_t)(t * 16 + m) * 128 + kc + quad * 8);
      acc[t] = __builtin_amdgcn_mfma_f32_16x16x32_f16(a, b, acc[t], 0, 0, 0);
    }
  }

  float rs[4];
  if constexpr (ROWSCALE) {
#pragma unroll
    for (int i = 0; i < 4; i++) {
      int r = rowTop + quad * 4 + i;
      rs[i] = rowscale[r < M ? r : M - 1];
    }
  }
#pragma unroll
  for (int t = 0; t < NT; t++)
#pragma unroll
    for (int i = 0; i < 4; i++) {
      float v = acc[t][i];
      if constexpr (BIASRELU) v = fmaxf(v, 0.0f);
      if constexpr (ROWSCALE) v *= rs[i];
      tile[w][quad * 4 + i][t * 16 + m] = __float2half(v);
    }
  __syncthreads();

  // vectorized row-major store: 8-half chunks, 16*BN/8 chunks per wave
  constexpr int CH = 16 * BN / 8;
#pragma unroll
  for (int rep = 0; rep < CH / 64; rep++) {
    int idx = rep * 64 + l;
    int r = idx / (BN / 8), cc = idx % (BN / 8);
    int grow = rowTop + r;
    if (grow < M)
      *reinterpret_cast<float4*>(C + (size_t)grow * BN + cc * 8) =
          *reinterpret_cast<const float4*>(&tile[w][r][cc * 8]);
  }
}

extern "C" void kernel_launch(void* const* d_in, const int* in_sizes, int n_in,
                              void* d_out, int out_size, void* d_ws, size_t ws_size,
                              hipStream_t stream) {
  const float* x  = (const float*)d_in[0];
  const int*   ei = (const int*)d_in[1];  // [2, NE] row-major
  const int* rows = ei;
  const int* cols = ei + NE;
  const float* W1 = (const float*)d_in[3];
  const float* b1 = (const float*)d_in[4];
  const float* W2 = (const float*)d_in[5];
  const float* b2 = (const float*)d_in[6];
  float* out = (float*)d_out;

  // ---- workspace carve (~90 MB) ----
  char* base = (char*)d_ws;
  constexpr size_t MB = 1 << 20;
  int*      deg      = (int*)(base + 0 * MB);
  int*      rowptr   = (int*)(base + 1 * MB);   // start pointers (never mutated)
  float*    dinv     = (float*)(base + 2 * MB);
  int*      blockSum = (int*)(base + 3 * MB);
  int*      blockOff = (int*)(base + 3 * MB + 4096);
  __half*   Wt1      = (__half*)(base + 3 * MB + 64 * 1024);   // 32 KB
  __half*   Wt2      = (__half*)(base + 3 * MB + 128 * 1024);  // 16 KB
  int*      table    = (int*)(base + 4 * MB);   // 803 KB
  int*      start    = (int*)(base + 5 * MB);   // 803 KB
  unsigned* binned   = (unsigned*)(base + 6 * MB);   // 6.4 MB
  int*      srcIdx   = (int*)(base + 13 * MB);       // 6.4 MB
  __half2*  y        = (__half2*)(base + 20 * MB);   // 25.6 MB (reused for z)
  __half*   aggx     = (__half*)(base + 46 * MB);    // 25.6 MB
  __half*   h1       = (__half*)(base + 72 * MB);    // 25.6 MB
  __half2*  z        = (__half2*)(base + 20 * MB);   // 12.8 MB (y dead)

  constexpr int SCAN_BLOCKS = (NN + 1023) / 1024;  // 98

  hipMemsetAsync(deg, 0, NN * sizeof(int), stream);
  k_wt<<<64, 256, 0, stream>>>(W1, Wt1, 128, 128);
  k_wt<<<32, 256, 0, stream>>>(W2, Wt2, 128, 64);
  k_deg<<<NBLK, 256, 0, stream>>>(cols, deg, table);
  k_scanA<<<SCAN_BLOCKS, 256, 0, stream>>>(deg, rowptr, blockSum);
  k_scanB<<<1, 128, 0, stream>>>(blockSum, blockOff, SCAN_BLOCKS);
  k_scanC<<<(NN + 255) / 256, 256, 0, stream>>>(rowptr, blockOff, deg, dinv);
  k_scanT<<<NB, 256, 0, stream>>>(table, rowptr, start);
  k_scat<<<NBLK, 256, 0, stream>>>(rows, cols, start, binned);
  k_fillb<<<NB, 256, 0, stream>>>(binned, rowptr, srcIdx);
  k_y<<<(NN * 32 + 255) / 256, 256, 0, stream>>>((const float4*)x, dinv, (float2*)y);
  k_gath1<<<(NN + 3) / 4, 256, 0, stream>>>(y, rowptr, deg, srcIdx, dinv,
                                            (__half2*)aggx);
  k_gemmM<128, true, false><<<(NN + 63) / 64, 256, 0, stream>>>(
      aggx, Wt1, b1, nullptr, h1, NN);
  k_gemmM<64, false, true><<<(NN + 63) / 64, 256, 0, stream>>>(
      h1, Wt2, nullptr, dinv, (__half*)z, NN);
  k_gath2<<<(NN + 7) / 8, 256, 0, stream>>>(z, rowptr, deg, srcIdx, dinv, b2,
                                            (float2*)out);
}

// Round 8
// 329.859 us; speedup vs baseline: 1.5474x; 1.1679x over previous
//
#include <hip/hip_runtime.h>
#include <hip/hip_fp16.h>

// GCN 2-layer, CSR-gather formulation, fp16 storage / fp32 math, MFMA GEMMs.
//   y = half(x * dinv)
//   aggX[c] = half( dinv[c] * (y[c] + sum_{r in in(c)} y[r]) )
//   h1 = half( relu(aggX @ W1 + b1) )          [MFMA f16, fp32 acc]
//   z  = half( (h1 @ W2) * dinv )              [MFMA f16, fp32 acc]
//   out[c] = fp32( dinv[c] * (z[c] + sum z[r]) + b2 )
// CSR build is fully deterministic and uses NO global atomics anywhere:
// per-block bucket histograms -> column scan -> bucket-base scan -> LDS-counter
// scatter -> per-bucket fill (which also derives per-node deg/rowptr/dinv from
// LDS counts). Rounds 1/3/4/7 lesson: random global atomics/stores write
// ~32-64B HBM lines per op (k_deg: 50 MB written for a 400 KB array); every
// scatter target region must be owned by ONE block so L2 merges full lines.

constexpr int NN = 100000;   // nodes
constexpr int NE = 1600000;  // edges
constexpr int BSH = 7;       // 128 nodes per bucket
constexpr int NB = (NN + 127) >> BSH;  // 782 buckets
constexpr int NBLK = 256;    // binning blocks
constexpr int EPB = NE / NBLK;  // 6250 edges per block (exact)
constexpr int TSTR = 784;    // table row stride (ints)

typedef _Float16 f16x8 __attribute__((ext_vector_type(8)));
typedef float f32x4 __attribute__((ext_vector_type(4)));

// ------------- per-(block,bucket) histogram (LDS atomics only) ---------------
__global__ __launch_bounds__(256) void k_hist(const int* __restrict__ cols,
                                              int* __restrict__ table) {
  __shared__ int cnt[NB];
  for (int i = threadIdx.x; i < NB; i += 256) cnt[i] = 0;
  __syncthreads();
  int base = blockIdx.x * EPB;
  for (int i = threadIdx.x; i < EPB; i += 256)
    atomicAdd(&cnt[cols[base + i] >> BSH], 1);
  __syncthreads();
  for (int i = threadIdx.x; i < NB; i += 256)
    table[blockIdx.x * TSTR + i] = cnt[i];
}

// ------- scan table columns over blocks: startOff + bucket totals ------------
__global__ __launch_bounds__(256) void k_scanT(const int* __restrict__ table,
                                               int* __restrict__ startOff,
                                               int* __restrict__ btot) {
  __shared__ int s[256];
  int b = blockIdx.x, t = threadIdx.x;
  int v = table[t * TSTR + b];
  s[t] = v;
  __syncthreads();
  for (int off = 1; off < 256; off <<= 1) {
    int tmp = (t >= off) ? s[t - off] : 0;
    __syncthreads();
    s[t] += tmp;
    __syncthreads();
  }
  startOff[t * TSTR + b] = s[t] - v;
  if (t == 255) btot[b] = s[t];
}

// ------- exclusive scan of 782 bucket totals -> bucketBase (1 block) ---------
__global__ __launch_bounds__(256) void k_scanBkt(const int* __restrict__ btot,
                                                 int* __restrict__ bucketBase) {
  __shared__ int s[256];
  int t = threadIdx.x;
  int base = t * 4;
  int d0 = (base + 0 < NB) ? btot[base + 0] : 0;
  int d1 = (base + 1 < NB) ? btot[base + 1] : 0;
  int d2 = (base + 2 < NB) ? btot[base + 2] : 0;
  int d3 = (base + 3 < NB) ? btot[base + 3] : 0;
  int tsum = d0 + d1 + d2 + d3;
  s[t] = tsum;
  __syncthreads();
  for (int off = 1; off < 256; off <<= 1) {
    int tmp = (t >= off) ? s[t - off] : 0;
    __syncthreads();
    s[t] += tmp;
    __syncthreads();
  }
  int ex = s[t] - tsum;
  if (base + 0 < NB) bucketBase[base + 0] = ex;
  if (base + 1 < NB) bucketBase[base + 1] = ex + d0;
  if (base + 2 < NB) bucketBase[base + 2] = ex + d0 + d1;
  if (base + 3 < NB) bucketBase[base + 3] = ex + d0 + d1 + d2;
}

// ------- scatter edges into bucket-grouped array (LDS counters only) ---------
__global__ __launch_bounds__(256) void k_scat(const int* __restrict__ rows,
                                              const int* __restrict__ cols,
                                              const int* __restrict__ startOff,
                                              const int* __restrict__ bucketBase,
                                              unsigned* __restrict__ binned) {
  __shared__ int scnt[NB];
  int blk = blockIdx.x;
  for (int i = threadIdx.x; i < NB; i += 256)
    scnt[i] = bucketBase[i] + startOff[blk * TSTR + i];
  __syncthreads();
  int base = blk * EPB;
  for (int i = threadIdx.x; i < EPB; i += 256) {
    int c = cols[base + i];
    int r = rows[base + i];
    int pos = atomicAdd(&scnt[c >> BSH], 1);
    binned[pos] = ((unsigned)r << BSH) | (unsigned)(c & 127);
  }
}

// ------- per-bucket fill: derive deg/rowptr/dinv + node-grouped srcIdx -------
// one block per bucket; block exclusively owns all its output ranges
__global__ __launch_bounds__(256) void k_fillb(const unsigned* __restrict__ binned,
                                               const int* __restrict__ bucketBase,
                                               const int* __restrict__ btot,
                                               int* __restrict__ rowptr,
                                               int* __restrict__ deg,
                                               float* __restrict__ dinv,
                                               int* __restrict__ srcIdx) {
  __shared__ int cnt[128];
  __shared__ int sc[128];
  __shared__ int rp[128];
  int b = blockIdx.x;
  int nb0 = b << BSH;
  int nn = min(128, NN - nb0);
  int tid = threadIdx.x;
  if (tid < 128) cnt[tid] = 0;
  __syncthreads();
  int ebeg = bucketBase[b];
  int eend = ebeg + btot[b];
  // pass 1: local degree count
  for (int p = ebeg + tid; p < eend; p += 256)
    atomicAdd(&cnt[binned[p] & 127], 1);
  __syncthreads();
  // block scan of the 128 local degrees
  int v = (tid < 128) ? cnt[tid] : 0;
  if (tid < 128) sc[tid] = v;
  __syncthreads();
  for (int off = 1; off < 128; off <<= 1) {
    int tmp = (tid < 128 && tid >= off) ? sc[tid - off] : 0;
    __syncthreads();
    if (tid < 128) sc[tid] += tmp;
    __syncthreads();
  }
  if (tid < 128) {
    int ex = sc[tid] - v;
    rp[tid] = ebeg + ex;
    if (tid < nn) {
      rowptr[nb0 + tid] = ebeg + ex;
      deg[nb0 + tid] = v;
      dinv[nb0 + tid] = rsqrtf((float)v + 1.0f);
    }
    cnt[tid] = 0;
  }
  __syncthreads();
  // pass 2: scatter srcIdx (node-grouped, contiguous per bucket)
  for (int p = ebeg + tid; p < eend; p += 256) {
    unsigned pk = binned[p];
    int cl = pk & 127;
    int local = atomicAdd(&cnt[cl], 1);
    srcIdx[rp[cl] + local] = (int)(pk >> BSH);
  }
}

// ------------- weight convert+transpose: W [K][N] f32 -> Wt [N][K] f16 -------
__global__ __launch_bounds__(256) void k_wt(const float* __restrict__ W,
                                            __half* __restrict__ Wt, int K, int N) {
  int i = blockIdx.x * 256 + threadIdx.x;
  if (i < K * N) {
    int k = i / N, n = i % N;
    Wt[n * K + k] = __float2half(W[i]);
  }
}

// ---------------- y = half(x * dinv) ----------------
__global__ __launch_bounds__(256) void k_y(const float4* __restrict__ x4,
                                           const float* __restrict__ dinv,
                                           float2* __restrict__ y8) {
  int gid = blockIdx.x * 256 + threadIdx.x;  // NN*32 float4 units
  if (gid >= NN * 32) return;
  float s = dinv[gid >> 5];
  float4 v = x4[gid];
  union { __half2 h[2]; float2 f; } u;
  u.h[0] = __floats2half2_rn(v.x * s, v.y * s);
  u.h[1] = __floats2half2_rn(v.z * s, v.w * s);
  y8[gid] = u.f;
}

// ---------------- gather-aggregate, width 128 half (wave per node) -----------
__global__ __launch_bounds__(256) void k_gath1(const __half2* __restrict__ y2,
                                               const int* __restrict__ rowptr,
                                               const int* __restrict__ deg,
                                               const int* __restrict__ srcIdx,
                                               const float* __restrict__ dinv,
                                               __half2* __restrict__ agg) {
  int node = blockIdx.x * 4 + (threadIdx.x >> 6);
  int lane = threadIdx.x & 63;
  if (node >= NN) return;
  int d = deg[node];
  int p = rowptr[node];  // start
  size_t rb = (size_t)node * 64 + lane;
  float2 acc = __half22float2(y2[rb]);  // self-loop term
  for (int base = 0; base < d; base += 64) {
    int cnt = min(64, d - base);
    int my = (lane < cnt) ? srcIdx[p + base + lane] : 0;
    int k = 0;
    for (; k + 4 <= cnt; k += 4) {
      int s0 = __shfl(my, k);
      int s1 = __shfl(my, k + 1);
      int s2 = __shfl(my, k + 2);
      int s3 = __shfl(my, k + 3);
      float2 v0 = __half22float2(y2[(size_t)s0 * 64 + lane]);
      float2 v1 = __half22float2(y2[(size_t)s1 * 64 + lane]);
      float2 v2 = __half22float2(y2[(size_t)s2 * 64 + lane]);
      float2 v3 = __half22float2(y2[(size_t)s3 * 64 + lane]);
      acc.x += v0.x + v1.x + v2.x + v3.x;
      acc.y += v0.y + v1.y + v2.y + v3.y;
    }
    for (; k < cnt; k++) {
      int s0 = __shfl(my, k);
      float2 v0 = __half22float2(y2[(size_t)s0 * 64 + lane]);
      acc.x += v0.x;
      acc.y += v0.y;
    }
  }
  float sc = dinv[node];
  agg[rb] = __floats2half2_rn(acc.x * sc, acc.y * sc);
}

// ---------------- gather-aggregate, width 64 half (half-wave per node) -------
__global__ __launch_bounds__(256) void k_gath2(const __half2* __restrict__ z2,
                                               const int* __restrict__ rowptr,
                                               const int* __restrict__ deg,
                                               const int* __restrict__ srcIdx,
                                               const float* __restrict__ dinv,
                                               const float* __restrict__ b2,
                                               float2* __restrict__ out2) {
  int node = blockIdx.x * 8 + (threadIdx.x >> 5);
  int lane = threadIdx.x & 31;
  if (node >= NN) return;
  int d = deg[node];
  int p = rowptr[node];
  float2 acc = __half22float2(z2[(size_t)node * 32 + lane]);
  for (int base = 0; base < d; base += 32) {
    int cnt = min(32, d - base);
    int my = (lane < cnt) ? srcIdx[p + base + lane] : 0;
    int k = 0;
    for (; k + 4 <= cnt; k += 4) {
      int s0 = __shfl(my, k, 32);
      int s1 = __shfl(my, k + 1, 32);
      int s2 = __shfl(my, k + 2, 32);
      int s3 = __shfl(my, k + 3, 32);
      float2 v0 = __half22float2(z2[(size_t)s0 * 32 + lane]);
      float2 v1 = __half22float2(z2[(size_t)s1 * 32 + lane]);
      float2 v2 = __half22float2(z2[(size_t)s2 * 32 + lane]);
      float2 v3 = __half22float2(z2[(size_t)s3 * 32 + lane]);
      acc.x += v0.x + v1.x + v2.x + v3.x;
      acc.y += v0.y + v1.y + v2.y + v3.y;
    }
    for (; k < cnt; k++) {
      int s0 = __shfl(my, k, 32);
      float2 v0 = __half22float2(z2[(size_t)s0 * 32 + lane]);
      acc.x += v0.x;
      acc.y += v0.y;
    }
  }
  float s = dinv[node];
  float2 bv = reinterpret_cast<const float2*>(b2)[lane];
  out2[(size_t)node * 32 + lane] = make_float2(acc.x * s + bv.x, acc.y * s + bv.y);
}

// ---- MFMA GEMM: C[M,BN] = A[M,128] @ W[128,BN], f16 in, fp32 acc, f16 out ---
// A fragment: lane holds A[row = rowTop + (l&15)][kc + (l>>4)*8 + j], j=0..7
// B fragment: lane holds Wt[col = t*16 + (l&15)][kc + (l>>4)*8 + j]
// C/D:        lane reg i = C[rowTop + (l>>4)*4 + i][t*16 + (l&15)]  (m89)
template <int BN, bool BIASRELU, bool ROWSCALE>
__global__ __launch_bounds__(256) void k_gemmM(const __half* __restrict__ A,
                                               const __half* __restrict__ Wt,
                                               const float* __restrict__ bias,
                                               const float* __restrict__ rowscale,
                                               __half* __restrict__ C, int M) {
  constexpr int NT = BN / 16;  // 8 or 4 col tiles per wave
  __shared__ __half tile[4][16][BN + 8];  // +8 pad: breaks 4-quad bank overlap
  const int w = threadIdx.x >> 6, l = threadIdx.x & 63;
  const int quad = l >> 4, m = l & 15;
  const int rowTop = blockIdx.x * 64 + w * 16;

  f32x4 acc[NT];
#pragma unroll
  for (int t = 0; t < NT; t++) {
    float bv = BIASRELU ? bias[t * 16 + m] : 0.0f;
    acc[t] = (f32x4){bv, bv, bv, bv};
  }

  int arow = rowTop + m;
  if (arow >= M) arow = M - 1;  // clamp: garbage rows computed but not stored
  const __half* ap = A + (size_t)arow * 128 + quad * 8;

#pragma unroll
  for (int kc = 0; kc < 128; kc += 32) {
    f16x8 a = *reinterpret_cast<const f16x8*>(ap + kc);
#pragma unroll
    for (int t = 0; t < NT; t++) {
      f16x8 b = *reinterpret_cast<const f16x8*>(
          Wt + (size_t)(t * 16 + m) * 128 + kc + quad * 8);
      acc[t] = __builtin_amdgcn_mfma_f32_16x16x32_f16(a, b, acc[t], 0, 0, 0);
    }
  }

  float rs[4];
  if constexpr (ROWSCALE) {
#pragma unroll
    for (int i = 0; i < 4; i++) {
      int r = rowTop + quad * 4 + i;
      rs[i] = rowscale[r < M ? r : M - 1];
    }
  }
#pragma unroll
  for (int t = 0; t < NT; t++)
#pragma unroll
    for (int i = 0; i < 4; i++) {
      float v = acc[t][i];
      if constexpr (BIASRELU) v = fmaxf(v, 0.0f);
      if constexpr (ROWSCALE) v *= rs[i];
      tile[w][quad * 4 + i][t * 16 + m] = __float2half(v);
    }
  __syncthreads();

  // vectorized row-major store: 8-half chunks
  constexpr int CH = 16 * BN / 8;
#pragma unroll
  for (int rep = 0; rep < CH / 64; rep++) {
    int idx = rep * 64 + l;
    int r = idx / (BN / 8), cc = idx % (BN / 8);
    int grow = rowTop + r;
    if (grow < M)
      *reinterpret_cast<float4*>(C + (size_t)grow * BN + cc * 8) =
          *reinterpret_cast<const float4*>(&tile[w][r][cc * 8]);
  }
}

extern "C" void kernel_launch(void* const* d_in, const int* in_sizes, int n_in,
                              void* d_out, int out_size, void* d_ws, size_t ws_size,
                              hipStream_t stream) {
  const float* x  = (const float*)d_in[0];
  const int*   ei = (const int*)d_in[1];  // [2, NE] row-major
  const int* rows = ei;
  const int* cols = ei + NE;
  const float* W1 = (const float*)d_in[3];
  const float* b1 = (const float*)d_in[4];
  const float* W2 = (const float*)d_in[5];
  const float* b2 = (const float*)d_in[6];
  float* out = (float*)d_out;

  // ---- workspace carve (~90 MB) ----
  char* base = (char*)d_ws;
  constexpr size_t MB = 1 << 20;
  int*      deg       = (int*)(base + 0 * MB);
  int*      rowptr    = (int*)(base + 1 * MB);
  float*    dinv      = (float*)(base + 2 * MB);
  int*      btot      = (int*)(base + 3 * MB);                  // 3.2 KB
  int*      bucketBase= (int*)(base + 3 * MB + 16 * 1024);      // 3.2 KB
  __half*   Wt1       = (__half*)(base + 3 * MB + 64 * 1024);   // 32 KB
  __half*   Wt2       = (__half*)(base + 3 * MB + 128 * 1024);  // 16 KB
  int*      table     = (int*)(base + 4 * MB);   // 803 KB
  int*      startOff  = (int*)(base + 5 * MB);   // 803 KB
  unsigned* binned    = (unsigned*)(base + 6 * MB);   // 6.4 MB
  int*      srcIdx    = (int*)(base + 13 * MB);       // 6.4 MB
  __half2*  y         = (__half2*)(base + 20 * MB);   // 25.6 MB (reused for z)
  __half*   aggx      = (__half*)(base + 46 * MB);    // 25.6 MB
  __half*   h1        = (__half*)(base + 72 * MB);    // 25.6 MB
  __half2*  z         = (__half2*)(base + 20 * MB);   // 12.8 MB (y dead)

  k_wt<<<64, 256, 0, stream>>>(W1, Wt1, 128, 128);
  k_wt<<<32, 256, 0, stream>>>(W2, Wt2, 128, 64);
  k_hist<<<NBLK, 256, 0, stream>>>(cols, table);
  k_scanT<<<NB, 256, 0, stream>>>(table, startOff, btot);
  k_scanBkt<<<1, 256, 0, stream>>>(btot, bucketBase);
  k_scat<<<NBLK, 256, 0, stream>>>(rows, cols, startOff, bucketBase, binned);
  k_fillb<<<NB, 256, 0, stream>>>(binned, bucketBase, btot, rowptr, deg, dinv,
                                  srcIdx);
  k_y<<<(NN * 32 + 255) / 256, 256, 0, stream>>>((const float4*)x, dinv, (float2*)y);
  k_gath1<<<(NN + 3) / 4, 256, 0, stream>>>(y, rowptr, deg, srcIdx, dinv,
                                            (__half2*)aggx);
  k_gemmM<128, true, false><<<(NN + 63) / 64, 256, 0, stream>>>(
      aggx, Wt1, b1, nullptr, h1, NN);
  k_gemmM<64, false, true><<<(NN + 63) / 64, 256, 0, stream>>>(
      h1, Wt2, nullptr, dinv, (__half*)z, NN);
  k_gath2<<<(NN + 7) / 8, 256, 0, stream>>>(z, rowptr, deg, srcIdx, dinv, b2,
                                            (float2*)out);
}